// Round 1
// baseline (634.153 us; speedup 1.0000x reference)
//
#include <hip/hip_runtime.h>

// ---------------------------------------------------------------------------
// GATv2 x2 + classifier. N=50000, E=800000, IN=128, HEADS=4, HID=32, OUT=16.
// Plan:
//   1. Build CSR (by dst) once per call: count -> scan -> scatter.
//   2. Layer: xl = x@Wl, xr = x@Wr (fp32 tiled GEMM, W staged in LDS)
//      then one wave per node walks its incoming edges (+implicit self loop)
//      doing online-softmax attention (no float atomics, no e materialized).
//   3. h1 lives in d_out's h-region (overwritten by layer-2 output later).
//   4. classifier: logits = h @ Wc + bc.
// ---------------------------------------------------------------------------

__global__ __launch_bounds__(256) void zero_i32(int* __restrict__ p, int n) {
  int i = blockIdx.x * 256 + threadIdx.x;
  if (i < n) p[i] = 0;
}

__global__ __launch_bounds__(256) void count_kernel(const int* __restrict__ dst,
                                                    int* __restrict__ cnt, int E) {
  int i = blockIdx.x * 256 + threadIdx.x;
  if (i < E) atomicAdd(&cnt[dst[i]], 1);
}

// single-block exclusive scan over n<=1024*CH counts -> row_start[0..n]
__global__ __launch_bounds__(1024) void scan_kernel(const int* __restrict__ cnt,
                                                    int* __restrict__ row_start, int n) {
  __shared__ int s[1024];
  int t = threadIdx.x;
  int CH = (n + 1023) >> 10;
  int base = t * CH;
  int lim = min(base + CH, n);
  int sum = 0;
  for (int i = base; i < lim; ++i) sum += cnt[i];
  s[t] = sum;
  __syncthreads();
  for (int off = 1; off < 1024; off <<= 1) {
    int v = (t >= off) ? s[t - off] : 0;
    __syncthreads();
    s[t] += v;
    __syncthreads();
  }
  int run = s[t] - sum;  // exclusive prefix
  for (int i = base; i < lim; ++i) { row_start[i] = run; run += cnt[i]; }
  if (t == 1023) row_start[n] = s[1023];
}

__global__ __launch_bounds__(256) void init_wpos(const int* __restrict__ row_start,
                                                 int* __restrict__ wpos, int n) {
  int i = blockIdx.x * 256 + threadIdx.x;
  if (i < n) wpos[i] = row_start[i];
}

__global__ __launch_bounds__(256) void scatter_kernel(const int* __restrict__ src,
                                                      const int* __restrict__ dst,
                                                      int* __restrict__ wpos,
                                                      int* __restrict__ csr, int E) {
  int i = blockIdx.x * 256 + threadIdx.x;
  if (i < E) {
    int d = dst[i];
    int p = atomicAdd(&wpos[d], 1);
    csr[p] = src[i];
  }
}

// C[nrows x 128] = A[nrows x 128] @ W[128 x 128], fp32.
// 64-row tile/block, 256 thr, each thread 4 rows x 8 cols, K chunked by 32.
__global__ __launch_bounds__(256) void gemm128_f32(const float* __restrict__ A,
                                                   const float* __restrict__ W,
                                                   float* __restrict__ C, int nrows) {
  __shared__ __align__(16) float sW[32 * 128];
  __shared__ float sA[64 * 33];  // +1 pad: a-reads land 2 addrs/bank (free)
  int tid = threadIdx.x;
  int rowBase = blockIdx.x * 64;
  int tx = tid & 15, ty = tid >> 4;
  int c0 = tx * 8;
  float acc[4][8];
#pragma unroll
  for (int j = 0; j < 4; ++j)
#pragma unroll
    for (int i = 0; i < 8; ++i) acc[j][i] = 0.f;

  for (int kc = 0; kc < 4; ++kc) {
    // A tile: 64 rows x 32 k = 512 float4, 2 per thread
#pragma unroll
    for (int i = 0; i < 2; ++i) {
      int idx = tid + i * 256;  // 0..511
      int row = idx >> 3, f4 = idx & 7;
      float4 v = make_float4(0.f, 0.f, 0.f, 0.f);
      int gr = rowBase + row;
      if (gr < nrows) v = *(const float4*)&A[(size_t)gr * 128 + kc * 32 + f4 * 4];
      int o = row * 33 + f4 * 4;
      sA[o] = v.x; sA[o + 1] = v.y; sA[o + 2] = v.z; sA[o + 3] = v.w;
    }
    // W tile: 32 k x 128 cols = 1024 float4, 4 per thread
#pragma unroll
    for (int i = 0; i < 4; ++i) {
      int idx = tid + i * 256;  // 0..1023
      int k = idx >> 5, f4 = idx & 31;
      *(float4*)&sW[k * 128 + f4 * 4] =
          *(const float4*)&W[(size_t)(kc * 32 + k) * 128 + f4 * 4];
    }
    __syncthreads();
#pragma unroll
    for (int kk = 0; kk < 32; ++kk) {
      float4 w0 = *(const float4*)&sW[kk * 128 + c0];
      float4 w1 = *(const float4*)&sW[kk * 128 + c0 + 4];
      float wv[8] = {w0.x, w0.y, w0.z, w0.w, w1.x, w1.y, w1.z, w1.w};
#pragma unroll
      for (int j = 0; j < 4; ++j) {
        float a = sA[(ty * 4 + j) * 33 + kk];
#pragma unroll
        for (int i = 0; i < 8; ++i) acc[j][i] = fmaf(a, wv[i], acc[j][i]);
      }
    }
    __syncthreads();
  }
#pragma unroll
  for (int j = 0; j < 4; ++j) {
    int gr = rowBase + ty * 4 + j;
    if (gr < nrows) {
      *(float4*)&C[(size_t)gr * 128 + c0] =
          make_float4(acc[j][0], acc[j][1], acc[j][2], acc[j][3]);
      *(float4*)&C[(size_t)gr * 128 + c0 + 4] =
          make_float4(acc[j][4], acc[j][5], acc[j][6], acc[j][7]);
    }
  }
}

// One wave per node; lane handles channels (2*lane, 2*lane+1) -> same head
// h = lane/16. Online softmax over incoming edges + self loop.
__global__ __launch_bounds__(256) void gat_attn(const float* __restrict__ xl,
                                                const float* __restrict__ xr,
                                                const int* __restrict__ row_start,
                                                const int* __restrict__ csr,
                                                const float* __restrict__ att,
                                                const float* __restrict__ bias,
                                                float* __restrict__ out, int n_nodes) {
  int node = blockIdx.x * 4 + (threadIdx.x >> 6);
  if (node >= n_nodes) return;
  int lane = threadIdx.x & 63;
  int c = lane * 2;
  float2 xrd = *(const float2*)&xr[(size_t)node * 128 + c];
  float ax = att[c], ay = att[c + 1];
  float m = -1e30f, lsum = 0.f, accx = 0.f, accy = 0.f;
  int beg = row_start[node], end = row_start[node + 1];
  for (int i = beg - 1; i < end; ++i) {  // i == beg-1 -> self loop
    int src = (i < beg) ? node : csr[i];
    float2 xs = *(const float2*)&xl[(size_t)src * 128 + c];
    float t0 = xs.x + xrd.x; t0 = (t0 > 0.f) ? t0 : 0.2f * t0;
    float t1 = xs.y + xrd.y; t1 = (t1 > 0.f) ? t1 : 0.2f * t1;
    float t = t0 * ax + t1 * ay;
    // sum over the 16-lane group (= one head's 32 channels)
    t += __shfl_xor(t, 1);
    t += __shfl_xor(t, 2);
    t += __shfl_xor(t, 4);
    t += __shfl_xor(t, 8);
    float e = t;
    float nm = fmaxf(m, e);
    float s = __expf(m - nm);
    float p = __expf(e - nm);
    lsum = lsum * s + p;
    accx = accx * s + p * xs.x;
    accy = accy * s + p * xs.y;
    m = nm;
  }
  float inv = 1.f / (lsum + 1e-16f);
  float ox = accx * inv + bias[c];
  float oy = accy * inv + bias[c + 1];
  ox = (ox > 0.f) ? ox : 0.01f * ox;
  oy = (oy > 0.f) ? oy : 0.01f * oy;
  *(float2*)&out[(size_t)node * 128 + c] = make_float2(ox, oy);
}

__global__ __launch_bounds__(256) void classifier_kernel(const float* __restrict__ h,
                                                         const float* __restrict__ Wc,
                                                         const float* __restrict__ bc,
                                                         float* __restrict__ logits,
                                                         int n) {
  int idx = blockIdx.x * 256 + threadIdx.x;
  if (idx >= n * 16) return;
  int node = idx >> 4, o = idx & 15;
  float acc = bc[o];
  const float* hrow = &h[(size_t)node * 128];
#pragma unroll
  for (int cc = 0; cc < 128; ++cc) acc = fmaf(hrow[cc], Wc[cc * 16 + o], acc);
  logits[idx] = acc;
}

extern "C" void kernel_launch(void* const* d_in, const int* in_sizes, int n_in,
                              void* d_out, int out_size, void* d_ws, size_t ws_size,
                              hipStream_t stream) {
  const float* x    = (const float*)d_in[0];
  const int*   ei   = (const int*)d_in[1];
  // d_in[2] edge_weight: unused by the reference
  const float* Wl1  = (const float*)d_in[3];
  const float* Wr1  = (const float*)d_in[4];
  const float* att1 = (const float*)d_in[5];
  const float* b1   = (const float*)d_in[6];
  const float* Wl2  = (const float*)d_in[7];
  const float* Wr2  = (const float*)d_in[8];
  const float* att2 = (const float*)d_in[9];
  const float* b2   = (const float*)d_in[10];
  const float* Wc   = (const float*)d_in[11];
  const float* bc   = (const float*)d_in[12];

  const int N = in_sizes[0] / 128;
  const int E = in_sizes[1] / 2;

  float* outp   = (float*)d_out;
  float* logits = outp;           // N*16
  float* hout   = outp + (size_t)N * 16;  // N*128 (also used as h1 staging)

  char* ws = (char*)d_ws;
  float* xl = (float*)ws;        ws += (size_t)N * 128 * 4;
  float* xr = (float*)ws;        ws += (size_t)N * 128 * 4;
  int* cnt       = (int*)ws;     ws += (size_t)N * 4;
  int* row_start = (int*)ws;     ws += (size_t)(N + 1) * 4;
  int* wpos      = (int*)ws;     ws += (size_t)N * 4;
  int* csr       = (int*)ws;     ws += (size_t)E * 4;

  const int* esrc = ei;
  const int* edst = ei + E;

  int gN = (N + 255) / 256, gE = (E + 255) / 256;
  int gGemm = (N + 63) / 64;
  int gAttn = (N + 3) / 4;

  // CSR build
  zero_i32<<<gN, 256, 0, stream>>>(cnt, N);
  count_kernel<<<gE, 256, 0, stream>>>(edst, cnt, E);
  scan_kernel<<<1, 1024, 0, stream>>>(cnt, row_start, N);
  init_wpos<<<gN, 256, 0, stream>>>(row_start, wpos, N);
  scatter_kernel<<<gE, 256, 0, stream>>>(esrc, edst, wpos, csr, E);

  // layer 1
  gemm128_f32<<<gGemm, 256, 0, stream>>>(x, Wl1, xl, N);
  gemm128_f32<<<gGemm, 256, 0, stream>>>(x, Wr1, xr, N);
  gat_attn<<<gAttn, 256, 0, stream>>>(xl, xr, row_start, csr, att1, b1, hout, N);

  // layer 2 (h1 staged in hout; overwritten below)
  gemm128_f32<<<gGemm, 256, 0, stream>>>(hout, Wl2, xl, N);
  gemm128_f32<<<gGemm, 256, 0, stream>>>(hout, Wr2, xr, N);
  gat_attn<<<gAttn, 256, 0, stream>>>(xl, xr, row_start, csr, att2, b2, hout, N);

  // classifier
  classifier_kernel<<<(N * 16 + 255) / 256, 256, 0, stream>>>(hout, Wc, bc, logits, N);
}